// Round 2
// baseline (5898.174 us; speedup 1.0000x reference)
//
#include <hip/hip_runtime.h>
#include <hip/hip_bf16.h>

#define N_NODES 16384
#define KNBR 10

// ---------------------------------------------------------------------------
// K1: per-modality embeds -> xcat [N,192]  (ReLU(Linear))
// ---------------------------------------------------------------------------
__global__ __launch_bounds__(256) void embed_kernel(
        const float* __restrict__ nf, const float* __restrict__ rf,
        const float* __restrict__ tf,
        const float* __restrict__ Wb, const float* __restrict__ bb,
        const float* __restrict__ Wr, const float* __restrict__ br,
        const float* __restrict__ Wt, const float* __restrict__ bt,
        float* __restrict__ xcat, int n) {
    int t = blockIdx.x * blockDim.x + threadIdx.x;
    if (t >= n * 192) return;
    int i = t / 192, o = t % 192;
    float acc;
    if (o < 64) {
        acc = bb[o];
        #pragma unroll
        for (int d = 0; d < 8; ++d) acc = fmaf(nf[i * 8 + d], Wb[d * 64 + o], acc);
    } else if (o < 128) {
        int oo = o - 64;
        acc = br[oo];
        #pragma unroll 8
        for (int d = 0; d < 64; ++d) acc = fmaf(rf[i * 64 + d], Wr[d * 64 + oo], acc);
    } else {
        int oo = o - 128;
        acc = bt[oo];
        #pragma unroll 8
        for (int d = 0; d < 64; ++d) acc = fmaf(tf[i * 64 + d], Wt[d * 64 + oo], acc);
    }
    xcat[t] = fmaxf(acc, 0.0f);
}

// ---------------------------------------------------------------------------
// K2: fusion -> h [N,128]  (LeakyReLU(Linear))
// ---------------------------------------------------------------------------
__global__ __launch_bounds__(256) void fuse_kernel(
        const float* __restrict__ xcat, const float* __restrict__ Wf,
        const float* __restrict__ bf, float* __restrict__ h, int n) {
    int t = blockIdx.x * blockDim.x + threadIdx.x;
    if (t >= n * 128) return;
    int i = t >> 7, o = t & 127;
    float acc = bf[o];
    const float* xr = xcat + (size_t)i * 192;
    #pragma unroll 8
    for (int d = 0; d < 192; ++d) acc = fmaf(xr[d], Wf[d * 128 + o], acc);
    h[t] = acc > 0.f ? acc : 0.01f * acc;
}

// ---------------------------------------------------------------------------
// K3: row squared-norms (one wave per row)
// ---------------------------------------------------------------------------
__global__ void sqnorm_kernel(const float* __restrict__ x, float* __restrict__ sq,
                              int n, int D) {
    int w = (blockIdx.x * blockDim.x + threadIdx.x) >> 6;
    int lane = threadIdx.x & 63;
    if (w >= n) return;
    float s = 0.f;
    for (int d = lane; d < D; d += 64) {
        float v = x[(size_t)w * D + d];
        s = fmaf(v, v, s);
    }
    #pragma unroll
    for (int off = 32; off > 0; off >>= 1) s += __shfl_down(s, off);
    if (lane == 0) sq[w] = s;
}

// ---------------------------------------------------------------------------
// K4: fused pairwise-distance GEMM + per-row top-10 (exclude self)
//   block: 256 threads, TM=64 query rows; streams j in TJ=64 tiles.
//   thread micro-tile: 4 rows x 4 cols, rows (tid>>4)+16r, cols (tid&15)+16c
//   XOR-swizzled LDS (f4-unit granularity) -> av 16-lane broadcast (free),
//   bv 2-way (free per m136).
//   scan phase: thread r (<64) owns query row r's register top-10; strict <
//   insert in increasing-j order == jax.lax.top_k low-index tie-break.
// ---------------------------------------------------------------------------
template <int D>
__global__ __launch_bounds__(256) void knn_kernel(const float* __restrict__ x,
                                                  const float* __restrict__ sq,
                                                  int* __restrict__ idx, int n) {
    constexpr int TM = 64, TJ = 64;
    constexpr int KC = (D > 64 ? 64 : D);      // d-chunk for Xj staging
    constexpr int LD4i = D / 4;                // float4 per Xi row
    constexpr int LD4j = KC / 4;               // float4 per Xj row

    __shared__ float4 XiF[TM * LD4i];
    __shared__ float4 XjF[TJ * LD4j];
    __shared__ float Dt[TM][TJ + 1];
    __shared__ float sqj[TJ];

    const int tid = threadIdx.x;
    const int i0 = blockIdx.x * TM;

    // stage Xi (swizzled), coalesced float4
    for (int f = tid; f < TM * LD4i; f += 256) {
        int row = f / LD4i, d4 = f % LD4i;
        float4 v = *reinterpret_cast<const float4*>(x + (size_t)(i0 + row) * D + d4 * 4);
        XiF[row * LD4i + ((d4 ^ (row & 7)) & (LD4i - 1))] = v;
    }

    float my_sqi = 0.f;
    float bd[KNBR];
    int bi[KNBR];
    if (tid < TM) {
        my_sqi = sq[i0 + tid];
        #pragma unroll
        for (int q = 0; q < KNBR; ++q) { bd[q] = 3.4e38f; bi[q] = 0; }
    }

    // micro-tile coordinates: rows (tid>>4)+16r, cols (tid&15)+16c
    const int r0 = tid >> 4;
    const int c0 = tid & 15;
    int ribase[4], rimask[4], cjbase[4], cjmask[4];
    #pragma unroll
    for (int r = 0; r < 4; ++r) {
        int row = r0 + 16 * r;
        ribase[r] = row * LD4i;
        rimask[r] = row & 7;
    }
    #pragma unroll
    for (int c = 0; c < 4; ++c) {
        int row = c0 + 16 * c;
        cjbase[c] = row * LD4j;
        cjmask[c] = row & 7;
    }

    for (int jt = 0; jt < n; jt += TJ) {
        float acc[4][4];
        #pragma unroll
        for (int r = 0; r < 4; ++r)
            #pragma unroll
            for (int c = 0; c < 4; ++c) acc[r][c] = 0.f;

        #pragma unroll
        for (int s = 0; s < D / KC; ++s) {
            __syncthreads();  // previous tile's scan / previous chunk's compute done
            for (int f = tid; f < TJ * LD4j; f += 256) {
                int row = f / LD4j, d4 = f % LD4j;
                float4 v = *reinterpret_cast<const float4*>(
                    x + (size_t)(jt + row) * D + s * KC + d4 * 4);
                XjF[row * LD4j + ((d4 ^ (row & 7)) & (LD4j - 1))] = v;
            }
            if (s == 0 && tid < TJ) sqj[tid] = sq[jt + tid];
            __syncthreads();

            #pragma unroll 4
            for (int d4 = 0; d4 < LD4j; ++d4) {
                int q = s * LD4j + d4;  // true f4-column within D
                float4 av[4], bv[4];
                #pragma unroll
                for (int r = 0; r < 4; ++r)
                    av[r] = XiF[ribase[r] + ((q ^ rimask[r]) & (LD4i - 1))];
                #pragma unroll
                for (int c = 0; c < 4; ++c)
                    bv[c] = XjF[cjbase[c] + ((d4 ^ cjmask[c]) & (LD4j - 1))];
                #pragma unroll
                for (int r = 0; r < 4; ++r)
                    #pragma unroll
                    for (int c = 0; c < 4; ++c) {
                        acc[r][c] = fmaf(av[r].x, bv[c].x, acc[r][c]);
                        acc[r][c] = fmaf(av[r].y, bv[c].y, acc[r][c]);
                        acc[r][c] = fmaf(av[r].z, bv[c].z, acc[r][c]);
                        acc[r][c] = fmaf(av[r].w, bv[c].w, acc[r][c]);
                    }
            }
        }

        // dump raw dots to LDS tile
        #pragma unroll
        for (int r = 0; r < 4; ++r)
            #pragma unroll
            for (int c = 0; c < 4; ++c)
                Dt[r0 + 16 * r][c0 + 16 * c] = acc[r][c];
        __syncthreads();

        // scan: thread tid (<64) owns query row i0+tid
        if (tid < TM) {
            const int ig = i0 + tid;
            for (int c = 0; c < TJ; ++c) {
                int j = jt + c;
                float dist = my_sqi + sqj[c] - 2.0f * Dt[tid][c];
                if (dist < bd[KNBR - 1] && j != ig) {
                    bd[KNBR - 1] = dist;
                    bi[KNBR - 1] = j;
                    #pragma unroll
                    for (int q2 = KNBR - 2; q2 >= 0; --q2) {
                        if (bd[q2 + 1] < bd[q2]) {
                            float td = bd[q2]; bd[q2] = bd[q2 + 1]; bd[q2 + 1] = td;
                            int tj2 = bi[q2]; bi[q2] = bi[q2 + 1]; bi[q2 + 1] = tj2;
                        }
                    }
                }
            }
        }
        // next iteration's first __syncthreads() protects Xj/sqj/Dt reuse
    }

    if (tid < TM) {
        #pragma unroll
        for (int q = 0; q < KNBR; ++q) idx[(size_t)(i0 + tid) * KNBR + q] = bi[q];
    }
}

// ---------------------------------------------------------------------------
// K5: EdgeConv: out[i,o] = max_k leaky_relu( [x_i, x_j-x_i] @ W + b )
//   structure split: a_o = b_o + x_i . W_top[:,o] computed once per node.
//   block = 64 threads (thread = output channel o), NN=4 nodes per block.
//   xi/xd staged in LDS as float4; inner reads are same-address broadcast
//   ds_read_b128 (conflict-free), 4 d-values per read.
// ---------------------------------------------------------------------------
template <int D>
__global__ __launch_bounds__(64) void edgeconv_kernel(const float* __restrict__ x,
                                                      const int* __restrict__ idx,
                                                      const float* __restrict__ W,
                                                      const float* __restrict__ bias,
                                                      float* __restrict__ out, int n) {
    constexpr int NN = 4;
    constexpr int D4 = D / 4;
    const int base = blockIdx.x * NN;
    const int o = threadIdx.x;

    __shared__ float4 xi4[NN][D4];
    __shared__ float4 xd4[NN][KNBR][D4];
    float* xi = (float*)xi4;   // [NN][D] linear view
    float* xd = (float*)xd4;   // [NN][KNBR][D] linear view

    for (int nn = 0; nn < NN; ++nn)
        for (int d = o; d < D; d += 64) xi[nn * D + d] = x[(size_t)(base + nn) * D + d];
    __syncthreads();
    for (int nn = 0; nn < NN; ++nn)
        for (int k = 0; k < KNBR; ++k) {
            int j = idx[(size_t)(base + nn) * KNBR + k];
            for (int d = o; d < D; d += 64)
                xd[(nn * KNBR + k) * D + d] = x[(size_t)j * D + d] - xi[nn * D + d];
        }
    __syncthreads();

    // a[nn] = bias + x_i . W_top[:,o]
    float a[NN];
    float bo = bias[o];
    #pragma unroll
    for (int nn = 0; nn < NN; ++nn) a[nn] = bo;
    for (int d4 = 0; d4 < D4; ++d4) {
        float4 xv[NN];
        #pragma unroll
        for (int nn = 0; nn < NN; ++nn) xv[nn] = xi4[nn][d4];  // broadcast read
        #pragma unroll
        for (int e = 0; e < 4; ++e) {
            float w = W[(d4 * 4 + e) * 64 + o];
            #pragma unroll
            for (int nn = 0; nn < NN; ++nn)
                a[nn] = fmaf(((const float*)&xv[nn])[e], w, a[nn]);
        }
    }

    float m[NN];
    #pragma unroll
    for (int nn = 0; nn < NN; ++nn) m[nn] = -3.4e38f;
    for (int k = 0; k < KNBR; ++k) {
        float acc[NN];
        #pragma unroll
        for (int nn = 0; nn < NN; ++nn) acc[nn] = a[nn];
        for (int d4 = 0; d4 < D4; ++d4) {
            float4 xv[NN];
            #pragma unroll
            for (int nn = 0; nn < NN; ++nn) xv[nn] = xd4[nn][k][d4];  // broadcast read
            #pragma unroll
            for (int e = 0; e < 4; ++e) {
                float w = W[(D + d4 * 4 + e) * 64 + o];
                #pragma unroll
                for (int nn = 0; nn < NN; ++nn)
                    acc[nn] = fmaf(((const float*)&xv[nn])[e], w, acc[nn]);
            }
        }
        #pragma unroll
        for (int nn = 0; nn < NN; ++nn) {
            float v = acc[nn] > 0.f ? acc[nn] : 0.01f * acc[nn];
            m[nn] = fmaxf(m[nn], v);
        }
    }
    for (int nn = 0; nn < NN; ++nn) out[(size_t)(base + nn) * 64 + o] = m[nn];
}

// ---------------------------------------------------------------------------
// K6: classifier logits = [g1,g2] @ Wc + bc
// ---------------------------------------------------------------------------
__global__ void classifier_kernel(const float* __restrict__ g1, const float* __restrict__ g2,
                                  const float* __restrict__ Wc, const float* __restrict__ bc,
                                  float* __restrict__ out, int n) {
    int t = blockIdx.x * blockDim.x + threadIdx.x;
    if (t >= n * 16) return;
    int i = t >> 4, c = t & 15;
    float acc = bc[c];
    #pragma unroll 8
    for (int d = 0; d < 64; ++d) acc = fmaf(g1[(size_t)i * 64 + d], Wc[d * 16 + c], acc);
    #pragma unroll 8
    for (int d = 0; d < 64; ++d) acc = fmaf(g2[(size_t)i * 64 + d], Wc[(64 + d) * 16 + c], acc);
    out[t] = acc;
}

// ---------------------------------------------------------------------------
extern "C" void kernel_launch(void* const* d_in, const int* in_sizes, int n_in,
                              void* d_out, int out_size, void* d_ws, size_t ws_size,
                              hipStream_t stream) {
    const int n = N_NODES;
    const float* node_feat = (const float*)d_in[0];
    const float* rf_feat   = (const float*)d_in[1];
    const float* txp_feat  = (const float*)d_in[2];
    const float* Wb = (const float*)d_in[3];
    const float* bb = (const float*)d_in[4];
    const float* Wr = (const float*)d_in[5];
    const float* br = (const float*)d_in[6];
    const float* Wt = (const float*)d_in[7];
    const float* bt = (const float*)d_in[8];
    const float* Wf = (const float*)d_in[9];
    const float* bf = (const float*)d_in[10];
    const float* We1 = (const float*)d_in[11];
    const float* be1 = (const float*)d_in[12];
    const float* We2 = (const float*)d_in[13];
    const float* be2 = (const float*)d_in[14];
    const float* Wc = (const float*)d_in[15];
    const float* bc = (const float*)d_in[16];

    // workspace layout (fp32): xcat | h | sq | g1 | g2 | idx   (~29.3 MB)
    float* xcat = (float*)d_ws;
    float* h    = xcat + (size_t)n * 192;
    float* sqv  = h + (size_t)n * 128;
    float* g1   = sqv + n;
    float* g2   = g1 + (size_t)n * 64;
    int*   idx  = (int*)(g2 + (size_t)n * 64);

    embed_kernel<<<(n * 192 + 255) / 256, 256, 0, stream>>>(
        node_feat, rf_feat, txp_feat, Wb, bb, Wr, br, Wt, bt, xcat, n);
    fuse_kernel<<<(n * 128 + 255) / 256, 256, 0, stream>>>(xcat, Wf, bf, h, n);

    // layer 1: KNN on h (D=128) + EdgeConv -> g1
    sqnorm_kernel<<<(n * 64 + 255) / 256, 256, 0, stream>>>(h, sqv, n, 128);
    knn_kernel<128><<<n / 64, 256, 0, stream>>>(h, sqv, idx, n);
    edgeconv_kernel<128><<<n / 4, 64, 0, stream>>>(h, idx, We1, be1, g1, n);

    // layer 2: KNN on g1 (D=64) + EdgeConv -> g2
    sqnorm_kernel<<<(n * 64 + 255) / 256, 256, 0, stream>>>(g1, sqv, n, 64);
    knn_kernel<64><<<n / 64, 256, 0, stream>>>(g1, sqv, idx, n);
    edgeconv_kernel<64><<<n / 4, 64, 0, stream>>>(g1, idx, We2, be2, g2, n);

    classifier_kernel<<<(n * 16 + 255) / 256, 256, 0, stream>>>(g1, g2, Wc, bc,
                                                                (float*)d_out, n);
}